// Round 2
// baseline (301.839 us; speedup 1.0000x reference)
//
#include <hip/hip_runtime.h>
#include <hip/hip_bf16.h>
#include <stdint.h>

// Problem dims (fixed by reference): T=8192 tokens, H=2048 hidden, I=768 intermediate
// Inputs/outputs are FP32 (per reference); internal compute is bf16 MFMA
// (2%-relative threshold permits it; expected absmax err ~0.02 vs 0.074 budget).
#define T_DIM 8192
#define H_DIM 2048
#define I_DIM 768

typedef __bf16 bf16_t;
typedef bf16_t bf16x8 __attribute__((ext_vector_type(8)));   // 4 VGPRs, MFMA A/B frag
typedef bf16_t bf16x4 __attribute__((ext_vector_type(4)));
typedef float  f32x4  __attribute__((ext_vector_type(4)));   // MFMA C/D frag

// Async global->LDS, 16B per lane. LDS dest must be wave-uniform base + lane*16.
__device__ __forceinline__ void async_load16(const void* g, void* s) {
    __builtin_amdgcn_global_load_lds(
        (const __attribute__((address_space(1))) void*)g,
        (__attribute__((address_space(3))) void*)s, 16, 0, 0);
}

// ---------------------------------------------------------------------------
// Kernel 0: fp32 -> bf16 conversion of all four inputs into workspace.
// Grid-stride over float4 groups; memory-bound (~132 MB total traffic).
// ---------------------------------------------------------------------------
__global__ __launch_bounds__(256) void cvt_kernel(
    const float* __restrict__ X, const float* __restrict__ G,
    const float* __restrict__ U, const float* __restrict__ D,
    bf16_t* __restrict__ Xb, bf16_t* __restrict__ Gb,
    bf16_t* __restrict__ Ub, bf16_t* __restrict__ Db)
{
    const size_t N4X = (size_t)T_DIM * H_DIM / 4;   // 4,194,304
    const size_t N4W = (size_t)I_DIM * H_DIM / 4;   //   393,216 (same for all 3 weights)
    const size_t total = N4X + 3 * N4W;
    for (size_t i = (size_t)blockIdx.x * blockDim.x + threadIdx.x; i < total;
         i += (size_t)gridDim.x * blockDim.x) {
        const float* s; bf16_t* d; size_t j = i;
        if (j < N4X) { s = X; d = Xb; }
        else {
            j -= N4X;
            if (j < N4W) { s = G; d = Gb; }
            else { j -= N4W;
                if (j < N4W) { s = U; d = Ub; }
                else { j -= N4W; s = D; d = Db; } }
        }
        float4 v = ((const float4*)s)[j];
        bf16x4 o;
        o[0] = (bf16_t)v.x; o[1] = (bf16_t)v.y; o[2] = (bf16_t)v.z; o[3] = (bf16_t)v.w;
        ((bf16x4*)d)[j] = o;
    }
}

// ---------------------------------------------------------------------------
// Kernel 1: per 128x128 tile of [T, I], compute G = x@gate^T, U = x@up^T via
// MFMA, then h = silu(G)*U, store bf16 h to workspace.
// Block = 256 threads = 4 waves in 2x2 grid; each wave owns a 64x64 subtile.
// ---------------------------------------------------------------------------
__global__ __launch_bounds__(256) void gateup_kernel(
    const bf16_t* __restrict__ X,
    const bf16_t* __restrict__ Wg,
    const bf16_t* __restrict__ Wu,
    bf16_t* __restrict__ Hbuf)
{
    __shared__ __align__(16) bf16_t sA[128 * 32];   // x tile   [128 rows][32 k]
    __shared__ __align__(16) bf16_t sG[128 * 32];   // gate_w tile
    __shared__ __align__(16) bf16_t sU[128 * 32];   // up_w tile

    const int tid   = threadIdx.x;
    const int lane  = tid & 63;
    const int wave  = tid >> 6;
    const int waveM = wave >> 1;      // 0..1
    const int waveN = wave & 1;       // 0..1
    const int quad  = lane >> 4;      // 0..3
    const int lrow  = lane & 15;      // 0..15

    const int blockM = blockIdx.x;    // 0..63  (T/128)
    const int blockN = blockIdx.y;    // 0..5   (I/128)

    f32x4 accG[4][4], accU[4][4];
#pragma unroll
    for (int i = 0; i < 4; i++)
#pragma unroll
        for (int j = 0; j < 4; j++) { accG[i][j] = (f32x4)(0.f); accU[i][j] = (f32x4)(0.f); }

    // Staging: tile is 128 rows x 32 bf16 = 8 KiB = 512 x 16B segments; 256 threads
    // do 2 segments each. Segment s covers row = s/4, cols (s%4)*8 .. +7.
    const int s0 = tid, s1 = tid + 256;
    const int rA0 = s0 >> 2, cA0 = (s0 & 3) * 8;
    const int rA1 = s1 >> 2, cA1 = (s1 & 3) * 8;

    const bf16_t* Ab = X  + (size_t)(blockM * 128) * H_DIM;
    const bf16_t* Gb = Wg + (size_t)(blockN * 128) * H_DIM;
    const bf16_t* Ub = Wu + (size_t)(blockN * 128) * H_DIM;

    for (int k0 = 0; k0 < H_DIM; k0 += 32) {
        async_load16(Ab + (size_t)rA0 * H_DIM + k0 + cA0, &sA[s0 * 8]);
        async_load16(Ab + (size_t)rA1 * H_DIM + k0 + cA1, &sA[s1 * 8]);
        async_load16(Gb + (size_t)rA0 * H_DIM + k0 + cA0, &sG[s0 * 8]);
        async_load16(Gb + (size_t)rA1 * H_DIM + k0 + cA1, &sG[s1 * 8]);
        async_load16(Ub + (size_t)rA0 * H_DIM + k0 + cA0, &sU[s0 * 8]);
        async_load16(Ub + (size_t)rA1 * H_DIM + k0 + cA1, &sU[s1 * 8]);
        __syncthreads();   // compiler emits vmcnt(0) drain before s_barrier

        bf16x8 aF[4], gF[4], uF[4];
#pragma unroll
        for (int mi = 0; mi < 4; mi++) {
            int r = waveM * 64 + mi * 16 + lrow;
            aF[mi] = *(const bf16x8*)&sA[r * 32 + quad * 8];
        }
#pragma unroll
        for (int ni = 0; ni < 4; ni++) {
            int r = waveN * 64 + ni * 16 + lrow;
            gF[ni] = *(const bf16x8*)&sG[r * 32 + quad * 8];
            uF[ni] = *(const bf16x8*)&sU[r * 32 + quad * 8];
        }
        __syncthreads();   // frags in regs; next iter may overwrite LDS

#pragma unroll
        for (int mi = 0; mi < 4; mi++)
#pragma unroll
            for (int ni = 0; ni < 4; ni++) {
                accG[mi][ni] = __builtin_amdgcn_mfma_f32_16x16x32_bf16(aF[mi], gF[ni], accG[mi][ni], 0, 0, 0);
                accU[mi][ni] = __builtin_amdgcn_mfma_f32_16x16x32_bf16(aF[mi], uF[ni], accU[mi][ni], 0, 0, 0);
            }
    }

    // Epilogue: h = silu(g)*u, cast bf16, store. C/D layout: col=lane&15, row=quad*4+r.
#pragma unroll
    for (int mi = 0; mi < 4; mi++) {
#pragma unroll
        for (int ni = 0; ni < 4; ni++) {
#pragma unroll
            for (int r = 0; r < 4; r++) {
                int row = blockM * 128 + waveM * 64 + mi * 16 + quad * 4 + r;
                int col = blockN * 128 + waveN * 64 + ni * 16 + lrow;
                float g = accG[mi][ni][r];
                float u = accU[mi][ni][r];
                float h = (g / (1.f + __expf(-g))) * u;
                Hbuf[(size_t)row * I_DIM + col] = (bf16_t)h;
            }
        }
    }
}

// ---------------------------------------------------------------------------
// Kernel 2: out[T,H] = h @ down^T.  down_w is [H, I] row-major (K=I contiguous),
// same B^T GEMM structure. K = 768 -> 24 steps of 32. Output stored as FP32.
// ---------------------------------------------------------------------------
__global__ __launch_bounds__(256) void down_kernel(
    const bf16_t* __restrict__ Hbuf,
    const bf16_t* __restrict__ Wd,
    float* __restrict__ Out)
{
    __shared__ __align__(16) bf16_t sA[128 * 32];
    __shared__ __align__(16) bf16_t sB[128 * 32];

    const int tid   = threadIdx.x;
    const int lane  = tid & 63;
    const int wave  = tid >> 6;
    const int waveM = wave >> 1;
    const int waveN = wave & 1;
    const int quad  = lane >> 4;
    const int lrow  = lane & 15;

    const int blockM = blockIdx.x;    // 0..63  (T/128)
    const int blockN = blockIdx.y;    // 0..15  (H/128)

    f32x4 acc[4][4];
#pragma unroll
    for (int i = 0; i < 4; i++)
#pragma unroll
        for (int j = 0; j < 4; j++) acc[i][j] = (f32x4)(0.f);

    const int s0 = tid, s1 = tid + 256;
    const int rA0 = s0 >> 2, cA0 = (s0 & 3) * 8;
    const int rA1 = s1 >> 2, cA1 = (s1 & 3) * 8;

    const bf16_t* Ab = Hbuf + (size_t)(blockM * 128) * I_DIM;
    const bf16_t* Bb = Wd   + (size_t)(blockN * 128) * I_DIM;

    for (int k0 = 0; k0 < I_DIM; k0 += 32) {
        async_load16(Ab + (size_t)rA0 * I_DIM + k0 + cA0, &sA[s0 * 8]);
        async_load16(Ab + (size_t)rA1 * I_DIM + k0 + cA1, &sA[s1 * 8]);
        async_load16(Bb + (size_t)rA0 * I_DIM + k0 + cA0, &sB[s0 * 8]);
        async_load16(Bb + (size_t)rA1 * I_DIM + k0 + cA1, &sB[s1 * 8]);
        __syncthreads();

        bf16x8 aF[4], bF[4];
#pragma unroll
        for (int mi = 0; mi < 4; mi++) {
            int r = waveM * 64 + mi * 16 + lrow;
            aF[mi] = *(const bf16x8*)&sA[r * 32 + quad * 8];
        }
#pragma unroll
        for (int ni = 0; ni < 4; ni++) {
            int r = waveN * 64 + ni * 16 + lrow;
            bF[ni] = *(const bf16x8*)&sB[r * 32 + quad * 8];
        }
        __syncthreads();

#pragma unroll
        for (int mi = 0; mi < 4; mi++)
#pragma unroll
            for (int ni = 0; ni < 4; ni++)
                acc[mi][ni] = __builtin_amdgcn_mfma_f32_16x16x32_bf16(aF[mi], bF[ni], acc[mi][ni], 0, 0, 0);
    }

#pragma unroll
    for (int mi = 0; mi < 4; mi++) {
#pragma unroll
        for (int ni = 0; ni < 4; ni++) {
#pragma unroll
            for (int r = 0; r < 4; r++) {
                int row = blockM * 128 + waveM * 64 + mi * 16 + quad * 4 + r;
                int col = blockN * 128 + waveN * 64 + ni * 16 + lrow;
                Out[(size_t)row * H_DIM + col] = acc[mi][ni][r];
            }
        }
    }
}

extern "C" void kernel_launch(void* const* d_in, const int* in_sizes, int n_in,
                              void* d_out, int out_size, void* d_ws, size_t ws_size,
                              hipStream_t stream) {
    const float* x  = (const float*)d_in[0];  // [T, H] fp32
    const float* gw = (const float*)d_in[1];  // [I, H] fp32
    const float* uw = (const float*)d_in[2];  // [I, H] fp32
    const float* dw = (const float*)d_in[3];  // [H, I] fp32
    float* out = (float*)d_out;               // [T, H] fp32

    // Workspace layout (bf16), all 16B-aligned:
    //   [0)                x_bf   T*H  = 16,777,216 elems (33.55 MB)
    //   [x_bf end)         gw_bf  I*H  =  1,572,864 elems ( 3.15 MB)
    //   ...                uw_bf, dw_bf same size
    //   [weights end)      hbuf   T*I  =  6,291,456 elems (12.58 MB)
    bf16_t* xb = (bf16_t*)d_ws;
    bf16_t* gb = xb + (size_t)T_DIM * H_DIM;
    bf16_t* ub = gb + (size_t)I_DIM * H_DIM;
    bf16_t* db = ub + (size_t)I_DIM * H_DIM;
    bf16_t* hb = db + (size_t)I_DIM * H_DIM;

    cvt_kernel<<<2048, 256, 0, stream>>>(x, gw, uw, dw, xb, gb, ub, db);
    gateup_kernel<<<dim3(T_DIM / 128, I_DIM / 128), 256, 0, stream>>>(xb, gb, ub, hb);
    down_kernel<<<dim3(T_DIM / 128, H_DIM / 128), 256, 0, stream>>>(hb, db, out);
}

// Round 3
// 229.154 us; speedup vs baseline: 1.3172x; 1.3172x over previous
//
#include <hip/hip_runtime.h>
#include <hip/hip_bf16.h>
#include <stdint.h>

// Problem dims (fixed by reference): T=8192 tokens, H=2048 hidden, I=768 intermediate
// Inputs/outputs are FP32 (per reference); internal compute is bf16 MFMA
// (2%-relative threshold permits it; measured absmax 0.0156 vs 0.074 budget).
#define T_DIM 8192
#define H_DIM 2048
#define I_DIM 768

typedef __bf16 bf16_t;
typedef bf16_t bf16x8 __attribute__((ext_vector_type(8)));   // 4 VGPRs, MFMA A/B frag
typedef bf16_t bf16x4 __attribute__((ext_vector_type(4)));
typedef float  f32x4  __attribute__((ext_vector_type(4)));   // MFMA C/D frag

// Async global->LDS, 16B per lane. LDS dest must be wave-uniform base + lane*16.
__device__ __forceinline__ void async_load16(const void* g, void* s) {
    __builtin_amdgcn_global_load_lds(
        (const __attribute__((address_space(1))) void*)g,
        (__attribute__((address_space(3))) void*)s, 16, 0, 0);
}

// ---------------------------------------------------------------------------
// Kernel 0: fp32 -> bf16 conversion of all four inputs into workspace.
// Grid-stride over float4 groups; memory-bound (~198 MB total traffic ~31 us).
// ---------------------------------------------------------------------------
__global__ __launch_bounds__(256) void cvt_kernel(
    const float* __restrict__ X, const float* __restrict__ G,
    const float* __restrict__ U, const float* __restrict__ D,
    bf16_t* __restrict__ Xb, bf16_t* __restrict__ Gb,
    bf16_t* __restrict__ Ub, bf16_t* __restrict__ Db)
{
    const size_t N4X = (size_t)T_DIM * H_DIM / 4;   // 4,194,304
    const size_t N4W = (size_t)I_DIM * H_DIM / 4;   //   393,216 (same for all 3 weights)
    const size_t total = N4X + 3 * N4W;
    for (size_t i = (size_t)blockIdx.x * blockDim.x + threadIdx.x; i < total;
         i += (size_t)gridDim.x * blockDim.x) {
        const float* s; bf16_t* d; size_t j = i;
        if (j < N4X) { s = X; d = Xb; }
        else {
            j -= N4X;
            if (j < N4W) { s = G; d = Gb; }
            else { j -= N4W;
                if (j < N4W) { s = U; d = Ub; }
                else { j -= N4W; s = D; d = Db; } }
        }
        float4 v = ((const float4*)s)[j];
        bf16x4 o;
        o[0] = (bf16_t)v.x; o[1] = (bf16_t)v.y; o[2] = (bf16_t)v.z; o[3] = (bf16_t)v.w;
        ((bf16x4*)d)[j] = o;
    }
}

// ---------------------------------------------------------------------------
// Kernel 1: 128x64 (MxN) tile of [T, I]: G = x@gate^T, U = x@up^T via MFMA,
// h = silu(G)*U -> bf16 workspace. Grid 64x12 = 768 blocks = 3 blocks/CU
// (was 128x128 / 384 blocks = 1.5/CU -> occupancy-bound at 8.3%).
// Block = 256 threads, 4 waves 2x2; wave owns 64x32 of both G and U.
// ---------------------------------------------------------------------------
__global__ __launch_bounds__(256) void gateup_kernel(
    const bf16_t* __restrict__ X,
    const bf16_t* __restrict__ Wg,
    const bf16_t* __restrict__ Wu,
    bf16_t* __restrict__ Hbuf)
{
    __shared__ __align__(16) bf16_t sA[128 * 32];   // x tile       8 KB
    __shared__ __align__(16) bf16_t sG[64 * 32];    // gate_w tile  4 KB
    __shared__ __align__(16) bf16_t sU[64 * 32];    // up_w tile    4 KB

    const int tid   = threadIdx.x;
    const int lane  = tid & 63;
    const int wave  = tid >> 6;
    const int waveM = wave >> 1;      // 0..1 -> 64-row half
    const int waveN = wave & 1;       // 0..1 -> 32-col half
    const int quad  = lane >> 4;      // 0..3
    const int lrow  = lane & 15;      // 0..15

    const int blockM = blockIdx.x;    // 0..63  (T/128)
    const int blockN = blockIdx.y;    // 0..11  (I/64)

    f32x4 accG[4][2], accU[4][2];
#pragma unroll
    for (int i = 0; i < 4; i++)
#pragma unroll
        for (int j = 0; j < 2; j++) { accG[i][j] = (f32x4)(0.f); accU[i][j] = (f32x4)(0.f); }

    // A: 128x32 = 512 x 16B segments (2/thread); W: 64x32 = 256 segments (1/thread).
    // Segment s covers row = s/4, cols (s%4)*8 .. +7.
    const int s0 = tid, s1 = tid + 256;
    const int rA0 = s0 >> 2, cA0 = (s0 & 3) * 8;
    const int rA1 = s1 >> 2, cA1 = (s1 & 3) * 8;
    const int rW  = tid >> 2, cW  = (tid & 3) * 8;

    const bf16_t* Ab = X  + (size_t)(blockM * 128) * H_DIM;
    const bf16_t* Gb = Wg + (size_t)(blockN * 64) * H_DIM;
    const bf16_t* Ub = Wu + (size_t)(blockN * 64) * H_DIM;

    for (int k0 = 0; k0 < H_DIM; k0 += 32) {
        async_load16(Ab + (size_t)rA0 * H_DIM + k0 + cA0, &sA[s0 * 8]);
        async_load16(Ab + (size_t)rA1 * H_DIM + k0 + cA1, &sA[s1 * 8]);
        async_load16(Gb + (size_t)rW  * H_DIM + k0 + cW,  &sG[tid * 8]);
        async_load16(Ub + (size_t)rW  * H_DIM + k0 + cW,  &sU[tid * 8]);
        __syncthreads();   // vmcnt(0) drain + barrier

        bf16x8 aF[4], gF[2], uF[2];
#pragma unroll
        for (int mi = 0; mi < 4; mi++) {
            int r = waveM * 64 + mi * 16 + lrow;
            aF[mi] = *(const bf16x8*)&sA[r * 32 + quad * 8];
        }
#pragma unroll
        for (int ni = 0; ni < 2; ni++) {
            int r = waveN * 32 + ni * 16 + lrow;
            gF[ni] = *(const bf16x8*)&sG[r * 32 + quad * 8];
            uF[ni] = *(const bf16x8*)&sU[r * 32 + quad * 8];
        }
        __syncthreads();   // frags in regs; next iter overwrites LDS

#pragma unroll
        for (int mi = 0; mi < 4; mi++)
#pragma unroll
            for (int ni = 0; ni < 2; ni++) {
                accG[mi][ni] = __builtin_amdgcn_mfma_f32_16x16x32_bf16(aF[mi], gF[ni], accG[mi][ni], 0, 0, 0);
                accU[mi][ni] = __builtin_amdgcn_mfma_f32_16x16x32_bf16(aF[mi], uF[ni], accU[mi][ni], 0, 0, 0);
            }
    }

    // Epilogue: h = silu(g)*u, cast bf16. C/D layout: col=lane&15, row=quad*4+r.
#pragma unroll
    for (int mi = 0; mi < 4; mi++) {
#pragma unroll
        for (int ni = 0; ni < 2; ni++) {
#pragma unroll
            for (int r = 0; r < 4; r++) {
                int row = blockM * 128 + waveM * 64 + mi * 16 + quad * 4 + r;
                int col = blockN * 64 + waveN * 32 + ni * 16 + lrow;
                float g = accG[mi][ni][r];
                float u = accU[mi][ni][r];
                float h = (g / (1.f + __expf(-g))) * u;
                Hbuf[(size_t)row * I_DIM + col] = (bf16_t)h;
            }
        }
    }
}

// ---------------------------------------------------------------------------
// Kernel 2: out[T,H] = h @ down^T.  down_w is [H, I] row-major (K=I contiguous).
// 128x128 tiles, grid 64x16 = 1024 blocks (4/CU). K = 768 -> 24 steps of 32.
// Output stored as FP32.
// ---------------------------------------------------------------------------
__global__ __launch_bounds__(256) void down_kernel(
    const bf16_t* __restrict__ Hbuf,
    const bf16_t* __restrict__ Wd,
    float* __restrict__ Out)
{
    __shared__ __align__(16) bf16_t sA[128 * 32];
    __shared__ __align__(16) bf16_t sB[128 * 32];

    const int tid   = threadIdx.x;
    const int lane  = tid & 63;
    const int wave  = tid >> 6;
    const int waveM = wave >> 1;
    const int waveN = wave & 1;
    const int quad  = lane >> 4;
    const int lrow  = lane & 15;

    const int blockM = blockIdx.x;    // 0..63  (T/128)
    const int blockN = blockIdx.y;    // 0..15  (H/128)

    f32x4 acc[4][4];
#pragma unroll
    for (int i = 0; i < 4; i++)
#pragma unroll
        for (int j = 0; j < 4; j++) acc[i][j] = (f32x4)(0.f);

    const int s0 = tid, s1 = tid + 256;
    const int rA0 = s0 >> 2, cA0 = (s0 & 3) * 8;
    const int rA1 = s1 >> 2, cA1 = (s1 & 3) * 8;

    const bf16_t* Ab = Hbuf + (size_t)(blockM * 128) * I_DIM;
    const bf16_t* Bb = Wd   + (size_t)(blockN * 128) * I_DIM;

    for (int k0 = 0; k0 < I_DIM; k0 += 32) {
        async_load16(Ab + (size_t)rA0 * I_DIM + k0 + cA0, &sA[s0 * 8]);
        async_load16(Ab + (size_t)rA1 * I_DIM + k0 + cA1, &sA[s1 * 8]);
        async_load16(Bb + (size_t)rA0 * I_DIM + k0 + cA0, &sB[s0 * 8]);
        async_load16(Bb + (size_t)rA1 * I_DIM + k0 + cA1, &sB[s1 * 8]);
        __syncthreads();

        bf16x8 aF[4], bF[4];
#pragma unroll
        for (int mi = 0; mi < 4; mi++) {
            int r = waveM * 64 + mi * 16 + lrow;
            aF[mi] = *(const bf16x8*)&sA[r * 32 + quad * 8];
        }
#pragma unroll
        for (int ni = 0; ni < 4; ni++) {
            int r = waveN * 64 + ni * 16 + lrow;
            bF[ni] = *(const bf16x8*)&sB[r * 32 + quad * 8];
        }
        __syncthreads();

#pragma unroll
        for (int mi = 0; mi < 4; mi++)
#pragma unroll
            for (int ni = 0; ni < 4; ni++)
                acc[mi][ni] = __builtin_amdgcn_mfma_f32_16x16x32_bf16(aF[mi], bF[ni], acc[mi][ni], 0, 0, 0);
    }

#pragma unroll
    for (int mi = 0; mi < 4; mi++) {
#pragma unroll
        for (int ni = 0; ni < 4; ni++) {
#pragma unroll
            for (int r = 0; r < 4; r++) {
                int row = blockM * 128 + waveM * 64 + mi * 16 + quad * 4 + r;
                int col = blockN * 128 + waveN * 64 + ni * 16 + lrow;
                Out[(size_t)row * H_DIM + col] = acc[mi][ni][r];
            }
        }
    }
}

extern "C" void kernel_launch(void* const* d_in, const int* in_sizes, int n_in,
                              void* d_out, int out_size, void* d_ws, size_t ws_size,
                              hipStream_t stream) {
    const float* x  = (const float*)d_in[0];  // [T, H] fp32
    const float* gw = (const float*)d_in[1];  // [I, H] fp32
    const float* uw = (const float*)d_in[2];  // [I, H] fp32
    const float* dw = (const float*)d_in[3];  // [H, I] fp32
    float* out = (float*)d_out;               // [T, H] fp32

    // Workspace layout (bf16): x_bf [T*H], gw_bf/uw_bf/dw_bf [I*H], hbuf [T*I].
    bf16_t* xb = (bf16_t*)d_ws;
    bf16_t* gb = xb + (size_t)T_DIM * H_DIM;
    bf16_t* ub = gb + (size_t)I_DIM * H_DIM;
    bf16_t* db = ub + (size_t)I_DIM * H_DIM;
    bf16_t* hb = db + (size_t)I_DIM * H_DIM;

    cvt_kernel<<<2048, 256, 0, stream>>>(x, gw, uw, dw, xb, gb, ub, db);
    gateup_kernel<<<dim3(T_DIM / 128, I_DIM / 64), 256, 0, stream>>>(xb, gb, ub, hb);
    down_kernel<<<dim3(T_DIM / 128, H_DIM / 128), 256, 0, stream>>>(hb, db, out);
}